// Round 11
// baseline (128.220 us; speedup 1.0000x reference)
//
#include <hip/hip_runtime.h>
#include <hip/hip_bf16.h>
#include <cstdint>

// CTC forward loss (keras ctc_batch_cost), B=64 T=1024 L=128 V=512.
// Two-phase:
//   K1 (gather, 4096 blocks): y_pred rows -> LDS -> gather 129 probs/(b,t),
//      pre-add EPSF, bf16-pack label pairs, GROUP-TRANSPOSED output:
//      pairs[(b*T+t)/4][lane][4] u32; blanks f32x4/group in blk[B*T].
//   K2 (scan, 32 blocks x 1 wave): TWO independent batch rows per wave
//      (b, b+32) with per-time-step interleaved STEP streams. r10 showed the
//      single-row chain runs ~140cy/step under in-order issue (full VALU/DPP/
//      readlane latency exposed, no independent work to fill stalls). The
//      second row's fully-register-disjoint stream fills every stall slot.
//      16-step phases, asm global_load_dwordx4 into named quads + counted
//      vmcnt(16) + sched_barrier (un-sinkable pipeline, rule #18).
//      Numerics per row byte-identical to r9/r10: renorm every 4 steps,
//      deferred one period, BIASE 90, DPP max-reduce, pow2-exact bookkeeping.
// Fallback to round-5 single kernel if ws too small.

#define CTC_B 64
#define CTC_T 1024
#define CTC_L 128
#define CTC_V 512
#define BLANK (CTC_V - 1)
#define EPSF 1e-7f
#define LN2F 0.69314718055994530942f
#define BIASE 90
#define K1ROWS 16

typedef __attribute__((ext_vector_type(4))) unsigned int u32x4;
typedef __attribute__((ext_vector_type(4))) float f32x4;

__device__ __forceinline__ void gld_lds16f(const float* g, float* l) {
    __builtin_amdgcn_global_load_lds(
        (const __attribute__((address_space(1))) unsigned int*)g,
        (__attribute__((address_space(3))) unsigned int*)l, 16, 0, 0);
}

template<int CTRL>
__device__ __forceinline__ float dpp_mov0(float v) {
    int r = __builtin_amdgcn_update_dpp(0, __float_as_int(v), CTRL, 0xf, 0xf, false);
    return __int_as_float(r);
}
template<int CTRL>
__device__ __forceinline__ float dpp_max(float v) {
    int r = __builtin_amdgcn_update_dpp(__float_as_int(v), __float_as_int(v),
                                        CTRL, 0xf, 0xf, false);
    return fmaxf(v, __int_as_float(r));
}
__device__ __forceinline__ uint32_t rne16(float x) {
    return (__float_as_uint(x) + 0x8000u) >> 16;
}

// ---------------- K1: gather + pack, group-transposed output ----------------
__global__ __launch_bounds__(256, 1)
void ctc_gather(const int* __restrict__ y_true,
                const float* __restrict__ y_pred,
                uint32_t* __restrict__ pairs,
                float* __restrict__ blk) {
    __shared__ __align__(16) float rows[K1ROWS][CTC_V];   // 32 KB

    const int bid = blockIdx.x;
    const int b = bid >> 6;
    const int t0 = (bid & 63) * K1ROWS;
    const int w = threadIdx.x >> 6;       // wave owns rows 4w..4w+3 = one group
    const int lane = threadIdx.x & 63;
    const float* __restrict__ yb = y_pred + ((size_t)b * CTC_T + t0) * CTC_V;

    const int2 lp = *(const int2*)&y_true[b * CTC_L + 2 * lane];

#pragma unroll
    for (int r = 0; r < 4; ++r) {
        const int row = 4 * w + r;
        const float* g = yb + (size_t)row * CTC_V + lane * 4;
        gld_lds16f(g, &rows[row][0]);
        gld_lds16f(g + 256, &rows[row][256]);
    }
    asm volatile("s_waitcnt vmcnt(0)" ::: "memory");

    uint32_t pk0, pk1, pk2, pk3;
    float bl0, bl1, bl2, bl3;
#define PACKROW(R) do {                                                    \
        const float* rowp = &rows[4 * w + (R)][0];                         \
        pk##R = rne16(rowp[lp.x] + EPSF) | (rne16(rowp[lp.y] + EPSF) << 16); \
        bl##R = rowp[BLANK] + EPSF;                                        \
    } while (0)
    PACKROW(0); PACKROW(1); PACKROW(2); PACKROW(3);
#undef PACKROW

    const size_t gidx = ((size_t)b * CTC_T + t0) / 4 + w;  // global group index
    u32x4 pv; pv.x = pk0; pv.y = pk1; pv.z = pk2; pv.w = pk3;
    ((u32x4*)pairs)[gidx * 64 + lane] = pv;                 // coalesced 1KB/wave
    if (lane == 0) {
        f32x4 bv; bv.x = bl0; bv.y = bl1; bv.z = bl2; bv.w = bl3;
        ((f32x4*)blk)[gidx] = bv;
    }
}

// ---------------- K2: dual-row asm-pipelined scan ----------------
#define GLD4(dst, addr, OFF)                                               \
    asm volatile("global_load_dwordx4 %0, %1, off offset:" OFF             \
                 : "=v"(dst) : "v"(addr) : "memory")

__global__ __launch_bounds__(64, 1)
void ctc_scan4(const int* __restrict__ y_true,
               const uint32_t* __restrict__ pairs,
               const float* __restrict__ blk,
               float* __restrict__ out) {
    const int b0 = blockIdx.x;          // row X
    const int b1 = b0 + CTC_B / 2;      // row Y
    const int lane = threadIdx.x;

    const uint8_t* px = (const uint8_t*)pairs + (size_t)b0 * 262144 + (size_t)lane * 16;
    const uint8_t* py = (const uint8_t*)pairs + (size_t)b1 * 262144 + (size_t)lane * 16;
    const uint8_t* bx = (const uint8_t*)blk + (size_t)b0 * 4096;   // wave-uniform
    const uint8_t* by = (const uint8_t*)blk + (size_t)b1 * 4096;

    // labels/masks, row X
    const int labAX = y_true[b0 * CTC_L + 2 * lane];
    const int labBX = y_true[b0 * CTC_L + 2 * lane + 1];
    const int labPX = __shfl_up(labBX, 1);
    const float msk1X = (labAX != labPX) ? 1.0f : 0.0f;
    const float msk3X = (labBX != labAX) ? 1.0f : 0.0f;
    // labels/masks, row Y
    const int labAY = y_true[b1 * CTC_L + 2 * lane];
    const int labBY = y_true[b1 * CTC_L + 2 * lane + 1];
    const int labPY = __shfl_up(labBY, 1);
    const float msk1Y = (labAY != labPY) ? 1.0f : 0.0f;
    const float msk3Y = (labBY != labAY) ? 1.0f : 0.0f;

    // pre-state: virtual "alpha[-1]" delta; t=0 is a uniform step
    float aX0 = (lane == 0) ? 1.0f : 0.0f;
    float aX1 = 0.0f, aX2 = 0.0f, aX3 = 0.0f, aX4 = 0.0f;
    float aY0 = (lane == 0) ? 1.0f : 0.0f;
    float aY1 = 0.0f, aY2 = 0.0f, aY3 = 0.0f, aY4 = 0.0f;
    float curScaleX = 1.0f, curScaleY = 1.0f;
    int curEX = 0, EaccX = 0, curEY = 0, EaccY = 0;

    // named prefetch quads: 2 rows x 2 sets x (4 pair + 4 blank) = 32 quads
    u32x4 PXA0, PXA1, PXA2, PXA3, PXB0, PXB1, PXB2, PXB3;
    u32x4 PYA0, PYA1, PYA2, PYA3, PYB0, PYB1, PYB2, PYB3;
    f32x4 QXA0, QXA1, QXA2, QXA3, QXB0, QXB1, QXB2, QXB3;
    f32x4 QYA0, QYA1, QYA2, QYA3, QYB0, QYB1, QYB2, QYB3;

#define ISSUE_PHASE(S) do {                                                \
        GLD4(PX##S##0, px, "0");    GLD4(PX##S##1, px, "1024");            \
        GLD4(PX##S##2, px, "2048"); GLD4(PX##S##3, px, "3072");            \
        GLD4(PY##S##0, py, "0");    GLD4(PY##S##1, py, "1024");            \
        GLD4(PY##S##2, py, "2048"); GLD4(PY##S##3, py, "3072");            \
        GLD4(QX##S##0, bx, "0");    GLD4(QX##S##1, bx, "16");              \
        GLD4(QX##S##2, bx, "32");   GLD4(QX##S##3, bx, "48");              \
        GLD4(QY##S##0, by, "0");    GLD4(QY##S##1, by, "16");              \
        GLD4(QY##S##2, by, "32");   GLD4(QY##S##3, by, "48");              \
        px += 4096; py += 4096; bx += 64; by += 64;                        \
    } while (0)

#define WAITP() do {                                                       \
        asm volatile("s_waitcnt vmcnt(16)" ::: "memory");                  \
        __builtin_amdgcn_sched_barrier(0);                                 \
    } while (0)

#define STEPR(R, vk, bv) do {                                              \
        const float pb_ = (bv);                                            \
        const float pA_ = __uint_as_float((vk) << 16);                     \
        const float pB_ = __uint_as_float((vk) & 0xffff0000u);             \
        const float pm1_ = dpp_mov0<0x138>(a##R##3); /* wave_shr:1 */      \
        const float n0_ = (a##R##0 + pm1_) * pb_;                          \
        const float n1_ = fmaf(msk1##R, pm1_, a##R##0 + a##R##1) * pA_;    \
        const float n2_ = (a##R##1 + a##R##2) * pb_;                       \
        const float n3_ = fmaf(msk3##R, a##R##1, a##R##2 + a##R##3) * pB_; \
        const float n4_ = (a##R##3 + a##R##4) * pb_;                       \
        a##R##0 = n0_; a##R##1 = n1_; a##R##2 = n2_;                       \
        a##R##3 = n3_; a##R##4 = n4_;                                      \
    } while (0)

#define DORNR(R) do {                                                      \
        a##R##0 *= curScale##R; a##R##1 *= curScale##R;                    \
        a##R##2 *= curScale##R; a##R##3 *= curScale##R;                    \
        a##R##4 *= curScale##R;                                            \
        Eacc##R += curE##R;                                                \
        float m_ = fmaxf(fmaxf(fmaxf(a##R##0, a##R##1),                    \
                               fmaxf(a##R##2, a##R##3)), a##R##4);         \
        m_ = dpp_max<0x111>(m_);  /* row_shr:1  */                         \
        m_ = dpp_max<0x112>(m_);  /* row_shr:2  */                         \
        m_ = dpp_max<0x114>(m_);  /* row_shr:4  */                         \
        m_ = dpp_max<0x118>(m_);  /* row_shr:8  */                         \
        m_ = dpp_max<0x142>(m_);  /* row_bcast:15 */                       \
        m_ = dpp_max<0x143>(m_);  /* row_bcast:31 */                       \
        const int mb_ = __builtin_amdgcn_readlane(__float_as_int(m_), 63); \
        const int e_ = (mb_ >> 23) & 255;                                  \
        int k_ = 127 + BIASE + 127 - e_;                                   \
        k_ = k_ > 254 ? 254 : (k_ < 1 ? 1 : k_);                           \
        curScale##R = __int_as_float((unsigned)k_ << 23);                  \
        curE##R = 127 - k_;                                                \
    } while (0)

#define GROUP(S, G) do {                                                   \
        STEPR(X, PX##S##G.x, QX##S##G.x); STEPR(Y, PY##S##G.x, QY##S##G.x);\
        STEPR(X, PX##S##G.y, QX##S##G.y); STEPR(Y, PY##S##G.y, QY##S##G.y);\
        STEPR(X, PX##S##G.z, QX##S##G.z); STEPR(Y, PY##S##G.z, QY##S##G.z);\
        STEPR(X, PX##S##G.w, QX##S##G.w); STEPR(Y, PY##S##G.w, QY##S##G.w);\
        DORNR(X); DORNR(Y);                                                \
    } while (0)

#define PROC_PHASE(S) do {                                                 \
        GROUP(S, 0); GROUP(S, 1); GROUP(S, 2); GROUP(S, 3);                \
    } while (0)

    ISSUE_PHASE(A);                 // phase 0 (16 loads)
    for (int it = 0; it < 32; ++it) {
        ISSUE_PHASE(B);             // next phase
        WAITP();                    // A ready (16 outstanding = B)
        PROC_PHASE(A);
        ISSUE_PHASE(A);             // (last iter: slack overread, unused)
        WAITP();                    // B ready
        PROC_PHASE(B);
    }

    if (lane == 63) {
        out[b0] = -(logf(aX3 + aX4) + (float)EaccX * LN2F);
        out[b1] = -(logf(aY3 + aY4) + (float)EaccY * LN2F);
    }
#undef PROC_PHASE
#undef GROUP
#undef DORNR
#undef STEPR
#undef WAITP
#undef ISSUE_PHASE
}
#undef GLD4

// ---------------- fallback: round-5 single kernel ----------------
#define F_CHUNK 16
#define F_NBUF  4
#define F_NCH   (CTC_T / F_CHUNK)

__global__ __launch_bounds__(256, 1)
void ctc_fwd_stream(const int* __restrict__ y_true,
                    const float* __restrict__ y_pred,
                    float* __restrict__ out) {
    __shared__ __align__(16) float rows[F_NBUF][F_CHUNK][CTC_V];
    const int b = blockIdx.x;
    const int tid = threadIdx.x;
    const int wave = tid >> 6;
    const int lane = tid & 63;
    const float* __restrict__ yb = y_pred + (size_t)b * CTC_T * CTC_V;

    if (wave != 0) {
        const int w = wave - 1;
#define FISSUE(c_) do {                                                    \
            const int t0_ = (c_) * F_CHUNK;                                \
            float* bufb_ = &rows[(c_) & (F_NBUF - 1)][0][0];               \
            for (int l_ = w; l_ < F_CHUNK; l_ += 3) {                      \
                const float* g_ = yb + (size_t)(t0_ + l_) * CTC_V + lane * 4; \
                float* d_ = bufb_ + l_ * CTC_V;                            \
                gld_lds16f(g_, d_);                                        \
                gld_lds16f(g_ + 256, d_ + 256);                            \
            }                                                              \
        } while (0)
        FISSUE(0); FISSUE(1); FISSUE(2);
        if (w == 0) asm volatile("s_waitcnt vmcnt(24)" ::: "memory");
        else        asm volatile("s_waitcnt vmcnt(20)" ::: "memory");
        __builtin_amdgcn_s_barrier();
        __builtin_amdgcn_sched_barrier(0);
        for (int c = 0; c < F_NCH; ++c) {
            if (c + 3 < F_NCH) FISSUE(c + 3);
            if (c <= F_NCH - 4) {
                if (w == 0) asm volatile("s_waitcnt vmcnt(24)" ::: "memory");
                else        asm volatile("s_waitcnt vmcnt(20)" ::: "memory");
            } else if (c == F_NCH - 3) {
                if (w == 0) asm volatile("s_waitcnt vmcnt(12)" ::: "memory");
                else        asm volatile("s_waitcnt vmcnt(10)" ::: "memory");
            } else if (c == F_NCH - 2) {
                asm volatile("s_waitcnt vmcnt(0)" ::: "memory");
            }
            __builtin_amdgcn_s_barrier();
            __builtin_amdgcn_sched_barrier(0);
        }
        return;
#undef FISSUE
    }

    const int labA = y_true[b * CTC_L + 2 * lane];
    const int labB = y_true[b * CTC_L + 2 * lane + 1];
    const int labPrev = __shfl_up(labB, 1);
    const float msk1 = (labA != labPrev) ? 1.0f : 0.0f;
    const float msk3 = (labB != labA) ? 1.0f : 0.0f;

    float a0 = 0.0f, a1 = 0.0f, a2 = 0.0f, a3 = 0.0f, a4 = 0.0f;
    float curScale = 1.0f;
    int curE = 0, Eacc = 0;
    float pAA0, pBA0, blA0, pAA1, pBA1, blA1, pAA2, pBA2, blA2, pAA3, pBA3, blA3;
    float pAB0, pBB0, blB0, pAB1, pBB1, blB1, pAB2, pBB2, blB2, pAB3, pBB3, blB3;
    float pAC0, pBC0, blC0, pAC1, pBC1, blC1, pAC2, pBC2, blC2, pAC3, pBC3, blC3;

#define FLOADG(S, l_) do {                                                 \
        const float* r0_ = bufc + ((l_) + 0) * CTC_V;                      \
        const float* r1_ = bufc + ((l_) + 1) * CTC_V;                      \
        const float* r2_ = bufc + ((l_) + 2) * CTC_V;                      \
        const float* r3_ = bufc + ((l_) + 3) * CTC_V;                      \
        pA##S##0 = r0_[labA]; pB##S##0 = r0_[labB]; bl##S##0 = r0_[BLANK]; \
        pA##S##1 = r1_[labA]; pB##S##1 = r1_[labB]; bl##S##1 = r1_[BLANK]; \
        pA##S##2 = r2_[labA]; pB##S##2 = r2_[labB]; bl##S##2 = r2_[BLANK]; \
        pA##S##3 = r3_[labA]; pB##S##3 = r3_[labB]; bl##S##3 = r3_[BLANK]; \
    } while (0)
#define FDOSTEP(S, k) do {                                                 \
        const float pb_ = bl##S##k + EPSF;                                 \
        const float pA_ = pA##S##k + EPSF;                                 \
        const float pB_ = pB##S##k + EPSF;                                 \
        const float pm1_ = dpp_mov0<0x138>(a3);                            \
        const float n0_ = (a0 + pm1_) * pb_;                               \
        const float n1_ = fmaf(msk1, pm1_, a0 + a1) * pA_;                 \
        const float n2_ = (a1 + a2) * pb_;                                 \
        const float n3_ = fmaf(msk3, a1, a2 + a3) * pB_;                   \
        const float n4_ = (a3 + a4) * pb_;                                 \
        a0 = n0_; a1 = n1_; a2 = n2_; a3 = n3_; a4 = n4_;                  \
    } while (0)
#define FDORN() do {                                                       \
        a0 *= curScale; a1 *= curScale; a2 *= curScale;                    \
        a3 *= curScale; a4 *= curScale;                                    \
        Eacc += curE;                                                      \
        float m_ = fmaxf(fmaxf(fmaxf(a0, a1), fmaxf(a2, a3)), a4);         \
        m_ = dpp_max<0x111>(m_); m_ = dpp_max<0x112>(m_);                  \
        m_ = dpp_max<0x114>(m_); m_ = dpp_max<0x118>(m_);                  \
        m_ = dpp_max<0x142>(m_); m_ = dpp_max<0x143>(m_);                  \
        const int mb_ = __builtin_amdgcn_readlane(__float_as_int(m_), 63); \
        const int e_ = (mb_ >> 23) & 255;                                  \
        int k_ = 127 + BIASE + 127 - e_;                                   \
        k_ = k_ > 254 ? 254 : (k_ < 1 ? 1 : k_);                           \
        curScale = __int_as_float((unsigned)k_ << 23);                     \
        curE = 127 - k_;                                                   \
    } while (0)
#define FPROC4_RN(S) do {                                                  \
        FDOSTEP(S, 0); FDORN();                                            \
        FDOSTEP(S, 1); FDOSTEP(S, 2); FDOSTEP(S, 3);                       \
    } while (0)

    __builtin_amdgcn_s_barrier();
    __builtin_amdgcn_sched_barrier(0);
    for (int c = 0; c < F_NCH; ++c) {
        const float* bufc = &rows[c & (F_NBUF - 1)][0][0];
        if (c == 0) {
            const float pb0 = bufc[BLANK] + EPSF;
            const float plA = bufc[labA] + EPSF;
            FLOADG(A, 0); FLOADG(B, 4); FLOADG(C, 8);
            a0 = (lane == 0) ? pb0 : 0.0f;
            a1 = (lane == 0) ? plA : 0.0f;
            FDOSTEP(A, 1); FDOSTEP(A, 2); FDOSTEP(A, 3);
            FLOADG(A, 12);
            FPROC4_RN(B); FPROC4_RN(C); FPROC4_RN(A);
        } else {
            FLOADG(A, 0); FLOADG(B, 4); FLOADG(C, 8);
            FPROC4_RN(A); FLOADG(A, 12);
            FPROC4_RN(B); FPROC4_RN(C); FPROC4_RN(A);
        }
        __builtin_amdgcn_s_barrier();
        __builtin_amdgcn_sched_barrier(0);
    }
    if (lane == 63) {
        out[b] = -(logf(a3 + a4) + (float)Eacc * LN2F);
    }
#undef FPROC4_RN
#undef FDORN
#undef FDOSTEP
#undef FLOADG
}

extern "C" void kernel_launch(void* const* d_in, const int* in_sizes, int n_in,
                              void* d_out, int out_size, void* d_ws, size_t ws_size,
                              hipStream_t stream) {
    (void)in_sizes; (void)n_in; (void)out_size;
    const int* y_true = (const int*)d_in[0];     // [B, L] int32
    const float* y_pred = (const float*)d_in[1]; // [B, T, V] float32
    float* out = (float*)d_out;                  // [B, 1] float32

    const size_t pairsBytes = (size_t)CTC_B * CTC_T * 64 * sizeof(uint32_t); // 16.78 MB
    const size_t blkBytes = (size_t)CTC_B * CTC_T * sizeof(float);           // 256 KB
    const size_t need = pairsBytes + blkBytes + 65536;                       // + overread slack
    if (ws_size >= need) {
        uint32_t* pairs = (uint32_t*)d_ws;
        float* blk = (float*)((char*)d_ws + pairsBytes);
        ctc_gather<<<CTC_B * (CTC_T / K1ROWS), 256, 0, stream>>>(y_true, y_pred, pairs, blk);
        ctc_scan4<<<CTC_B / 2, 64, 0, stream>>>(y_true, pairs, blk, out);
    } else {
        ctc_fwd_stream<<<CTC_B, 256, 0, stream>>>(y_true, y_pred, out);
    }
}